// Round 2
// baseline (211.379 us; speedup 1.0000x reference)
//
#include <hip/hip_runtime.h>

#define TEMP    0.5f
#define LOG2E   1.4426950408889634f
#define C2      (LOG2E / TEMP)        /* t = dot * C2 */
#define MSHIFT  160.0f                /* fixed base-2 softmax shift */
#define LN2     0.6931471805599453f
#define NROWS   16384
#define BHALF   8192
#define DDIM    128
#define PREPB   2048                  /* k_prep blocks = 524288/256 */

typedef __bf16 bf16x8 __attribute__((ext_vector_type(8)));
typedef float  f32x16 __attribute__((ext_vector_type(16)));

__device__ __forceinline__ float fexp2(float x) {
#if __has_builtin(__builtin_amdgcn_exp2f)
  return __builtin_amdgcn_exp2f(x);
#else
  return exp2f(x);
#endif
}

__device__ __forceinline__ unsigned short f2bf(float f) {
  unsigned int u = __float_as_uint(f);
  unsigned int r = (u + 0x7FFFu + ((u >> 16) & 1u)) >> 16;  // RNE
  return (unsigned short)r;
}

// ---------------------------------------------------------------------------
// zbF frag-major layout: for row r, k-index k:
//   g = r/32, lo = r%32, khi = k/8, j = k%8
//   short index = g*4096 + khi*256 + lo*8 + j
// A wave's frag load (fixed ks): 64 lanes read a contiguous 1KB block.
// ---------------------------------------------------------------------------

// k_prep: cast concat(z_i,z_j) fp32->bf16 into frag-major zbF; per-block
// partial dot(z_i,z_j) -> Pp[block]; zero S.
__global__ void k_prep(const float* __restrict__ zi, const float* __restrict__ zj,
                       unsigned short* __restrict__ zbF,
                       float* __restrict__ S, float* __restrict__ Pp) {
  const int t   = blockIdx.x * 256 + threadIdx.x;   // 0..524287 float4 groups
  const int row = t >> 5;                           // 32 float4 per 128-elt row
  const int k0  = (t & 31) * 4;
  const float* src = (row < BHALF) ? (zi + (size_t)row * DDIM)
                                   : (zj + (size_t)(row - BHALF) * DDIM);
  float4 v = *reinterpret_cast<const float4*>(src + k0);

  const int g = row >> 5, lo = row & 31, khi = k0 >> 3, j0 = k0 & 7;
  ushort4 o;
  o.x = f2bf(v.x); o.y = f2bf(v.y); o.z = f2bf(v.z); o.w = f2bf(v.w);
  *reinterpret_cast<ushort4*>(zbF + (size_t)g * 4096 + khi * 256 + lo * 8 + j0) = o;

  float dot = 0.f;
  if (row < BHALF) {
    float4 w = *reinterpret_cast<const float4*>(zj + (size_t)row * DDIM + k0);
    dot = fmaf(v.x, w.x, fmaf(v.y, w.y, fmaf(v.z, w.z, v.w * w.w)));
  }
#pragma unroll
  for (int m = 32; m >= 1; m >>= 1) dot += __shfl_xor(dot, m, 64);
  __shared__ float red[4];
  if ((threadIdx.x & 63) == 0) red[threadIdx.x >> 6] = dot;
  __syncthreads();
  if (threadIdx.x == 0) Pp[blockIdx.x] = red[0] + red[1] + red[2] + red[3];

  if (t < NROWS) S[t] = 0.f;
}

// ---------------------------------------------------------------------------
// k_main: wave holds 128 persistent rows as MFMA *B* operand (lane-indexed in
// C/D -> scalar row sums). Streams 32-col tiles as the A operand.
//
// Software pipeline: accumulators are double-buffered (accP = tiles 0,1 ;
// accQ = tiles 2,3). Each phase issues one 8-step MFMA chain-pair into one
// buffer while exp-ing the OTHER buffer (completed a full phase earlier),
// interleaved per-ks in source so the MFMA pipe and the VALU/trans pipe run
// concurrently instead of alternating.
// ---------------------------------------------------------------------------

template <bool MASK>
__device__ __forceinline__ void exp4(const f32x16& acc, int r0, float& sa, float& sb,
                                     int d, int hi) {
#pragma unroll
  for (int q = 0; q < 4; ++q) {
    const int r = r0 + q;
    float e = fexp2(fmaf(acc[r], C2, -MSHIFT));
    if (MASK) {
      const int rloc = (r & 3) + 8 * (r >> 2) + 4 * hi;  // col-part (C/D reg map)
      if (rloc == d) e = 0.f;
    }
    if (r & 1) sb += e; else sa += e;
  }
}

// One phase: build x0/x1 (16 MFMAs, chains over ks) from a[] x {bA,bB};
// concurrently exp the 32 elements of e0/e1 into s0*/s1*; optionally reload
// a[ks] (for the NEXT iteration's columns) right after its last use here.
template <bool MASK, bool RELOAD>
__device__ __forceinline__ void phase(bf16x8 (&a)[8],
                                      const bf16x8 (&bA)[8], const bf16x8 (&bB)[8],
                                      const unsigned short* __restrict__ ap,
                                      f32x16& x0, f32x16& x1,
                                      const f32x16& e0, const f32x16& e1,
                                      float& s0a, float& s0b, float& s1a, float& s1b,
                                      int d0, int d1, int hi) {
  const f32x16 kZ = {};
  x0 = __builtin_amdgcn_mfma_f32_32x32x16_bf16(a[0], bA[0], kZ, 0, 0, 0);
  x1 = __builtin_amdgcn_mfma_f32_32x32x16_bf16(a[0], bB[0], kZ, 0, 0, 0);
  if constexpr (RELOAD) a[0] = *reinterpret_cast<const bf16x8*>(ap);
  exp4<MASK>(e0, 0, s0a, s0b, d0, hi);
#pragma unroll
  for (int ks = 1; ks < 8; ++ks) {
    x0 = __builtin_amdgcn_mfma_f32_32x32x16_bf16(a[ks], bA[ks], x0, 0, 0, 0);
    x1 = __builtin_amdgcn_mfma_f32_32x32x16_bf16(a[ks], bB[ks], x1, 0, 0, 0);
    if constexpr (RELOAD)
      a[ks] = *reinterpret_cast<const bf16x8*>(ap + (size_t)ks * 512);
    if (ks < 4) exp4<MASK>(e0, ks * 4,       s0a, s0b, d0, hi);
    else        exp4<MASK>(e1, (ks - 4) * 4, s1a, s1b, d1, hi);
  }
}

template <bool MASK>
__device__ __forceinline__ void expTail(const f32x16& e0, const f32x16& e1,
                                        float& s0a, float& s0b, float& s1a, float& s1b,
                                        int d0, int d1, int hi) {
#pragma unroll
  for (int q = 0; q < 4; ++q) exp4<MASK>(e0, q * 4, s0a, s0b, d0, hi);
#pragma unroll
  for (int q = 0; q < 4; ++q) exp4<MASK>(e1, q * 4, s1a, s1b, d1, hi);
}

__global__ __launch_bounds__(256, 2)
void k_main(const unsigned short* __restrict__ zbF, float* __restrict__ S) {
  const int wave = threadIdx.x >> 6;
  const int lane = threadIdx.x & 63;
  const int lo = lane & 31;
  const int hi = lane >> 5;
  const int rb = blockIdx.x & 31;       // 32 row blocks of 512 rows
  const int cc = blockIdx.x >> 5;       // 16 col chunks of 1024 cols
  const int row0w = rb * 512 + wave * 128;

  // persistent row frags (B operand): 4 row-tiles x 8 k-steps = 128 VGPRs
  bf16x8 b[4][8];
#pragma unroll
  for (int rt = 0; rt < 4; ++rt) {
    const unsigned short* bp = zbF + (size_t)((row0w >> 5) + rt) * 4096 + hi * 256 + lo * 8;
#pragma unroll
    for (int ks = 0; ks < 8; ++ks)
      b[rt][ks] = *reinterpret_cast<const bf16x8*>(bp + ks * 512);
  }

  float s[4][2];
#pragma unroll
  for (int rt = 0; rt < 4; ++rt) { s[rt][0] = 0.f; s[rt][1] = 0.f; }

  const int c0base = cc * 1024;
  const unsigned short* abase = zbF + (size_t)(c0base >> 5) * 4096 + hi * 256 + lo * 8;

  bf16x8 a[8];
#pragma unroll
  for (int ks = 0; ks < 8; ++ks)
    a[ks] = *reinterpret_cast<const bf16x8*>(abase + ks * 512);

  f32x16 accP0, accP1, accQ0, accQ1;

  // prologue: phase A(0) — tiles 0,1 of it=0, nothing to exp yet
  {
    const f32x16 kZ = {};
    accP0 = __builtin_amdgcn_mfma_f32_32x32x16_bf16(a[0], b[0][0], kZ, 0, 0, 0);
    accP1 = __builtin_amdgcn_mfma_f32_32x32x16_bf16(a[0], b[1][0], kZ, 0, 0, 0);
#pragma unroll
    for (int ks = 1; ks < 8; ++ks) {
      accP0 = __builtin_amdgcn_mfma_f32_32x32x16_bf16(a[ks], b[0][ks], accP0, 0, 0, 0);
      accP1 = __builtin_amdgcn_mfma_f32_32x32x16_bf16(a[ks], b[1][ks], accP1, 0, 0, 0);
    }
  }

  for (int it = 0; it < 32; ++it) {
    const int c0 = c0base + it * 32;
    const int dr = c0 - row0w;
    const bool dg = (unsigned)dr < 128u;       // tile touches diagonal?
    const int rtd = dg ? (dr >> 5) : -1;
    const unsigned short* apn = abase + (size_t)(it + 1) * 4096;

    if (it < 31) {
      if (!dg) {
        // phase B(it): MFMA tiles 2,3 -> accQ ; exp accP (tiles 0,1 of it) ; reload a
        phase<false, true >(a, b[2], b[3], apn, accQ0, accQ1, accP0, accP1,
                            s[0][0], s[0][1], s[1][0], s[1][1], -1, -1, hi);
        // phase A(it+1): MFMA tiles 0,1 (new a) -> accP ; exp accQ (tiles 2,3 of it)
        phase<false, false>(a, b[0], b[1], abase, accP0, accP1, accQ0, accQ1,
                            s[2][0], s[2][1], s[3][0], s[3][1], -1, -1, hi);
      } else {
        phase<true, true >(a, b[2], b[3], apn, accQ0, accQ1, accP0, accP1,
                           s[0][0], s[0][1], s[1][0], s[1][1],
                           rtd == 0 ? lo : -1, rtd == 1 ? lo : -1, hi);
        phase<true, false>(a, b[0], b[1], abase, accP0, accP1, accQ0, accQ1,
                           s[2][0], s[2][1], s[3][0], s[3][1],
                           rtd == 2 ? lo : -1, rtd == 3 ? lo : -1, hi);
      }
    } else {
      if (!dg) {
        phase<false, false>(a, b[2], b[3], abase, accQ0, accQ1, accP0, accP1,
                            s[0][0], s[0][1], s[1][0], s[1][1], -1, -1, hi);
        expTail<false>(accQ0, accQ1, s[2][0], s[2][1], s[3][0], s[3][1], -1, -1, hi);
      } else {
        phase<true, false>(a, b[2], b[3], abase, accQ0, accQ1, accP0, accP1,
                           s[0][0], s[0][1], s[1][0], s[1][1],
                           rtd == 0 ? lo : -1, rtd == 1 ? lo : -1, hi);
        expTail<true>(accQ0, accQ1, s[2][0], s[2][1], s[3][0], s[3][1],
                      rtd == 2 ? lo : -1, rtd == 3 ? lo : -1, hi);
      }
    }
  }

  // row sums: lane-local scalar + fold hi halves, one atomic per row per chunk
#pragma unroll
  for (int rt = 0; rt < 4; ++rt) {
    float v = s[rt][0] + s[rt][1];
    v += __shfl_xor(v, 32, 64);
    if (hi == 0) atomicAdd(&S[row0w + rt * 32 + lo], v);
  }
}

// ---------------------------------------------------------------------------
// k_fin: out = ( LN2 * sum_k (M + log2 S_k)  -  4 * sum Pp ) / N
// Linear -> single fused block reduction (1024 threads).
// ---------------------------------------------------------------------------
__global__ void k_fin(const float* __restrict__ S, const float* __restrict__ Pp,
                      float* __restrict__ out) {
  const int t = threadIdx.x;            // 1024 threads
  float q = 0.f;
  for (int r = t; r < NROWS; r += 1024)
    q += LN2 * (MSHIFT + __log2f(S[r]));
  for (int r = t; r < PREPB; r += 1024)
    q -= 4.0f * Pp[r];
  __shared__ float red[1024];
  red[t] = q;
  __syncthreads();
  for (int s2 = 512; s2 > 0; s2 >>= 1) {
    if (t < s2) red[t] += red[t + s2];
    __syncthreads();
  }
  if (t == 0) out[0] = red[0] / (float)NROWS;
}

// ---------------------------------------------------------------------------
extern "C" void kernel_launch(void* const* d_in, const int* in_sizes, int n_in,
                              void* d_out, int out_size, void* d_ws, size_t ws_size,
                              hipStream_t stream) {
  const float* zi = (const float*)d_in[0];
  const float* zj = (const float*)d_in[1];
  unsigned short* zbF = (unsigned short*)d_ws;                     // 4 MB
  float* S  = (float*)((char*)d_ws + (size_t)NROWS * DDIM * 2);    // 64 KB
  float* Pp = S + NROWS;                                           // 8 KB
  float* out = (float*)d_out;

  hipLaunchKernelGGL(k_prep, dim3(PREPB), dim3(256), 0, stream, zi, zj, zbF, S, Pp);
  hipLaunchKernelGGL(k_main, dim3(512),  dim3(256), 0, stream, zbF, S);
  hipLaunchKernelGGL(k_fin,  dim3(1),    dim3(1024), 0, stream, S, Pp, out);
}

// Round 3
// 174.247 us; speedup vs baseline: 1.2131x; 1.2131x over previous
//
#include <hip/hip_runtime.h>

#define TEMP    0.5f
#define LOG2E   1.4426950408889634f
#define C2      (LOG2E / TEMP)        /* t = dot * C2 */
#define MSHIFT  160.0f                /* fixed base-2 softmax shift */
#define LN2     0.6931471805599453f
#define NROWS   16384
#define BHALF   8192
#define DDIM    128
#define PREPB   2048                  /* k_prep blocks = 524288/256 */

typedef __bf16 bf16x8 __attribute__((ext_vector_type(8)));
typedef float  f32x16 __attribute__((ext_vector_type(16)));

__device__ __forceinline__ float fexp2(float x) {
#if __has_builtin(__builtin_amdgcn_exp2f)
  return __builtin_amdgcn_exp2f(x);
#else
  return exp2f(x);
#endif
}

__device__ __forceinline__ unsigned short f2bf(float f) {
  unsigned int u = __float_as_uint(f);
  unsigned int r = (u + 0x7FFFu + ((u >> 16) & 1u)) >> 16;  // RNE
  return (unsigned short)r;
}

// ---------------------------------------------------------------------------
// zbF frag-major layout: for row r, k-index k:
//   g = r/32, lo = r%32, khi = k/8, j = k%8
//   short index = g*4096 + khi*256 + lo*8 + j
// A wave's frag load (fixed ks): 64 lanes read a contiguous 1KB block.
// ---------------------------------------------------------------------------

// k_prep: cast concat(z_i,z_j) fp32->bf16 into frag-major zbF; per-block
// partial dot(z_i,z_j) -> Pp[block]; zero S.
__global__ void k_prep(const float* __restrict__ zi, const float* __restrict__ zj,
                       unsigned short* __restrict__ zbF,
                       float* __restrict__ S, float* __restrict__ Pp) {
  const int t   = blockIdx.x * 256 + threadIdx.x;   // 0..524287 float4 groups
  const int row = t >> 5;                           // 32 float4 per 128-elt row
  const int k0  = (t & 31) * 4;
  const float* src = (row < BHALF) ? (zi + (size_t)row * DDIM)
                                   : (zj + (size_t)(row - BHALF) * DDIM);
  float4 v = *reinterpret_cast<const float4*>(src + k0);

  const int g = row >> 5, lo = row & 31, khi = k0 >> 3, j0 = k0 & 7;
  ushort4 o;
  o.x = f2bf(v.x); o.y = f2bf(v.y); o.z = f2bf(v.z); o.w = f2bf(v.w);
  *reinterpret_cast<ushort4*>(zbF + (size_t)g * 4096 + khi * 256 + lo * 8 + j0) = o;

  float dot = 0.f;
  if (row < BHALF) {
    float4 w = *reinterpret_cast<const float4*>(zj + (size_t)row * DDIM + k0);
    dot = fmaf(v.x, w.x, fmaf(v.y, w.y, fmaf(v.z, w.z, v.w * w.w)));
  }
#pragma unroll
  for (int m = 32; m >= 1; m >>= 1) dot += __shfl_xor(dot, m, 64);
  __shared__ float red[4];
  if ((threadIdx.x & 63) == 0) red[threadIdx.x >> 6] = dot;
  __syncthreads();
  if (threadIdx.x == 0) Pp[blockIdx.x] = red[0] + red[1] + red[2] + red[3];

  if (t < NROWS) S[t] = 0.f;
}

// ---------------------------------------------------------------------------
// k_main: wave holds 128 persistent rows as MFMA *B* operand (lane-indexed in
// C/D -> scalar row sums). Streams 32-col tiles as the A operand.
//
// Singleton-tile software pipeline (this revision): TWO acc buffers (accA,
// accB) ping-pong at per-tile granularity. Each phase issues one 8-step MFMA
// chain into one buffer while exp-ing the OTHER buffer (the tile finished one
// phase earlier), with 2 exps interleaved per MFMA step in source. Live acc
// registers = 2 x f32x16 = 32 VGPRs — same footprint as the non-pipelined
// baseline, so no spilling (round-1's 4-buffer variant spilled: WRITE_SIZE
// 1MB -> 28MB).
// ---------------------------------------------------------------------------

// exp elements r = 2*ks and 2*ks+1 of acc e into sa/sb.
template <bool MASK>
__device__ __forceinline__ void expStep2(const f32x16& e, int ks, float& sa, float& sb,
                                         int d, int hi) {
  {
    const int r = 2 * ks;
    float v = fexp2(fmaf(e[r], C2, -MSHIFT));
    if (MASK) {
      const int rloc = (r & 3) + 8 * (r >> 2) + 4 * hi;  // col-part (C/D reg map)
      if (rloc == d) v = 0.f;
    }
    sa += v;
  }
  {
    const int r = 2 * ks + 1;
    float v = fexp2(fmaf(e[r], C2, -MSHIFT));
    if (MASK) {
      const int rloc = (r & 3) + 8 * (r >> 2) + 4 * hi;
      if (rloc == d) v = 0.f;
    }
    sb += v;
  }
}

// One phase: build x (8-MFMA chain over ks) from a[] x bT; concurrently exp
// the 16 elements of e (previous tile) into sa/sb; optionally reload a[ks]
// (next iteration's columns) right after its last use in this chain.
template <bool MASK, bool RELOAD>
__device__ __forceinline__ void buildExp(bf16x8 (&a)[8], const bf16x8 (&bT)[8],
                                         const unsigned short* __restrict__ ap,
                                         f32x16& x, const f32x16& e,
                                         float& sa, float& sb, int d, int hi) {
  const f32x16 kZ = {};
  x = __builtin_amdgcn_mfma_f32_32x32x16_bf16(a[0], bT[0], kZ, 0, 0, 0);
  if constexpr (RELOAD) a[0] = *reinterpret_cast<const bf16x8*>(ap);
  expStep2<MASK>(e, 0, sa, sb, d, hi);
#pragma unroll
  for (int ks = 1; ks < 8; ++ks) {
    x = __builtin_amdgcn_mfma_f32_32x32x16_bf16(a[ks], bT[ks], x, 0, 0, 0);
    if constexpr (RELOAD)
      a[ks] = *reinterpret_cast<const bf16x8*>(ap + (size_t)ks * 512);
    expStep2<MASK>(e, ks, sa, sb, d, hi);
  }
}

// Drain: exp all 16 elements of e (no concurrent MFMA).
template <bool MASK>
__device__ __forceinline__ void expFull(const f32x16& e, float& sa, float& sb,
                                        int d, int hi) {
#pragma unroll
  for (int ks = 0; ks < 8; ++ks) expStep2<MASK>(e, ks, sa, sb, d, hi);
}

__global__ __launch_bounds__(256, 2)
void k_main(const unsigned short* __restrict__ zbF, float* __restrict__ S) {
  const int wave = threadIdx.x >> 6;
  const int lane = threadIdx.x & 63;
  const int lo = lane & 31;
  const int hi = lane >> 5;
  const int rb = blockIdx.x & 31;       // 32 row blocks of 512 rows
  const int cc = blockIdx.x >> 5;       // 16 col chunks of 1024 cols
  const int row0w = rb * 512 + wave * 128;

  // persistent row frags (B operand): 4 row-tiles x 8 k-steps = 128 VGPRs
  bf16x8 b[4][8];
#pragma unroll
  for (int rt = 0; rt < 4; ++rt) {
    const unsigned short* bp = zbF + (size_t)((row0w >> 5) + rt) * 4096 + hi * 256 + lo * 8;
#pragma unroll
    for (int ks = 0; ks < 8; ++ks)
      b[rt][ks] = *reinterpret_cast<const bf16x8*>(bp + ks * 512);
  }

  float s[4][2];
#pragma unroll
  for (int rt = 0; rt < 4; ++rt) { s[rt][0] = 0.f; s[rt][1] = 0.f; }

  const int c0base = cc * 1024;
  const unsigned short* abase = zbF + (size_t)(c0base >> 5) * 4096 + hi * 256 + lo * 8;

  bf16x8 a[8];
#pragma unroll
  for (int ks = 0; ks < 8; ++ks)
    a[ks] = *reinterpret_cast<const bf16x8*>(abase + ks * 512);

  f32x16 accA, accB;

  // prologue: build tile0 of it=0 into accA (nothing to exp yet)
  {
    const f32x16 kZ = {};
    accA = __builtin_amdgcn_mfma_f32_32x32x16_bf16(a[0], b[0][0], kZ, 0, 0, 0);
#pragma unroll
    for (int ks = 1; ks < 8; ++ks)
      accA = __builtin_amdgcn_mfma_f32_32x32x16_bf16(a[ks], b[0][ks], accA, 0, 0, 0);
  }

  for (int it = 0; it < 32; ++it) {
    const int c0 = c0base + it * 32;
    const int dr = c0 - row0w;
    const bool dg = (unsigned)dr < 128u;       // tile touches diagonal?
    const int rtd = dg ? (dr >> 5) : -1;
    const unsigned short* apn = abase + (size_t)(it + 1) * 4096;

    if (!dg) {
      // build tile1 -> accB ; exp accA = tile0(it)
      buildExp<false, false>(a, b[1], abase, accB, accA, s[0][0], s[0][1], -1, hi);
      // build tile2 -> accA ; exp accB = tile1(it)
      buildExp<false, false>(a, b[2], abase, accA, accB, s[1][0], s[1][1], -1, hi);
      // build tile3 -> accB ; exp accA = tile2(it) ; reload a for it+1
      buildExp<false, true >(a, b[3], apn,   accB, accA, s[2][0], s[2][1], -1, hi);
      if (it < 31)  // build tile0(it+1) -> accA (new a) ; exp accB = tile3(it)
        buildExp<false, false>(a, b[0], abase, accA, accB, s[3][0], s[3][1], -1, hi);
      else
        expFull<false>(accB, s[3][0], s[3][1], -1, hi);
    } else {
      buildExp<true, false>(a, b[1], abase, accB, accA, s[0][0], s[0][1],
                            rtd == 0 ? lo : -1, hi);
      buildExp<true, false>(a, b[2], abase, accA, accB, s[1][0], s[1][1],
                            rtd == 1 ? lo : -1, hi);
      buildExp<true, true >(a, b[3], apn,   accB, accA, s[2][0], s[2][1],
                            rtd == 2 ? lo : -1, hi);
      if (it < 31)
        buildExp<true, false>(a, b[0], abase, accA, accB, s[3][0], s[3][1],
                              rtd == 3 ? lo : -1, hi);
      else
        expFull<true>(accB, s[3][0], s[3][1], rtd == 3 ? lo : -1, hi);
    }
  }

  // row sums: lane-local scalar + fold hi halves, one atomic per row per chunk
#pragma unroll
  for (int rt = 0; rt < 4; ++rt) {
    float v = s[rt][0] + s[rt][1];
    v += __shfl_xor(v, 32, 64);
    if (hi == 0) atomicAdd(&S[row0w + rt * 32 + lo], v);
  }
}

// ---------------------------------------------------------------------------
// k_fin: out = ( LN2 * sum_k (M + log2 S_k)  -  4 * sum Pp ) / N
// Linear -> single fused block reduction (1024 threads).
// ---------------------------------------------------------------------------
__global__ void k_fin(const float* __restrict__ S, const float* __restrict__ Pp,
                      float* __restrict__ out) {
  const int t = threadIdx.x;            // 1024 threads
  float q = 0.f;
  for (int r = t; r < NROWS; r += 1024)
    q += LN2 * (MSHIFT + __log2f(S[r]));
  for (int r = t; r < PREPB; r += 1024)
    q -= 4.0f * Pp[r];
  __shared__ float red[1024];
  red[t] = q;
  __syncthreads();
  for (int s2 = 512; s2 > 0; s2 >>= 1) {
    if (t < s2) red[t] += red[t + s2];
    __syncthreads();
  }
  if (t == 0) out[0] = red[0] / (float)NROWS;
}

// ---------------------------------------------------------------------------
extern "C" void kernel_launch(void* const* d_in, const int* in_sizes, int n_in,
                              void* d_out, int out_size, void* d_ws, size_t ws_size,
                              hipStream_t stream) {
  const float* zi = (const float*)d_in[0];
  const float* zj = (const float*)d_in[1];
  unsigned short* zbF = (unsigned short*)d_ws;                     // 4 MB
  float* S  = (float*)((char*)d_ws + (size_t)NROWS * DDIM * 2);    // 64 KB
  float* Pp = S + NROWS;                                           // 8 KB
  float* out = (float*)d_out;

  hipLaunchKernelGGL(k_prep, dim3(PREPB), dim3(256), 0, stream, zi, zj, zbF, S, Pp);
  hipLaunchKernelGGL(k_main, dim3(512),  dim3(256), 0, stream, zbF, S);
  hipLaunchKernelGGL(k_fin,  dim3(1),    dim3(1024), 0, stream, S, Pp, out);
}

// Round 4
// 130.552 us; speedup vs baseline: 1.6191x; 1.3347x over previous
//
#include <hip/hip_runtime.h>

#define TEMP    0.5f
#define LOG2E   1.4426950408889634f
#define C2      (LOG2E / TEMP)        /* t = dot * C2 */
#define MSHIFT  160.0f                /* fixed base-2 softmax shift */
#define LN2     0.6931471805599453f
#define NROWS   16384
#define BHALF   8192
#define DDIM    128
#define PREPB   2048                  /* k_prep blocks = 524288/256 */

typedef __bf16 bf16x8 __attribute__((ext_vector_type(8)));
typedef float  f32x16 __attribute__((ext_vector_type(16)));
typedef float  f32x2  __attribute__((ext_vector_type(2)));

__device__ __forceinline__ float fexp2(float x) {
#if __has_builtin(__builtin_amdgcn_exp2f)
  return __builtin_amdgcn_exp2f(x);
#else
  return exp2f(x);
#endif
}

__device__ __forceinline__ unsigned short f2bf(float f) {
  unsigned int u = __float_as_uint(f);
  unsigned int r = (u + 0x7FFFu + ((u >> 16) & 1u)) >> 16;  // RNE
  return (unsigned short)r;
}

// ---------------------------------------------------------------------------
// zbF frag-major layout: for row r, k-index k:
//   g = r/32, lo = r%32, khi = k/8, j = k%8
//   short index = g*4096 + khi*256 + lo*8 + j
// A wave's frag load (fixed ks): 64 lanes read a contiguous 1KB block.
// ---------------------------------------------------------------------------

// k_prep: cast concat(z_i,z_j) fp32->bf16 into frag-major zbF; per-block
// partial dot(z_i,z_j) -> Pp[block]; zero S.
__global__ void k_prep(const float* __restrict__ zi, const float* __restrict__ zj,
                       unsigned short* __restrict__ zbF,
                       float* __restrict__ S, float* __restrict__ Pp) {
  const int t   = blockIdx.x * 256 + threadIdx.x;   // 0..524287 float4 groups
  const int row = t >> 5;                           // 32 float4 per 128-elt row
  const int k0  = (t & 31) * 4;
  const float* src = (row < BHALF) ? (zi + (size_t)row * DDIM)
                                   : (zj + (size_t)(row - BHALF) * DDIM);
  float4 v = *reinterpret_cast<const float4*>(src + k0);

  const int g = row >> 5, lo = row & 31, khi = k0 >> 3, j0 = k0 & 7;
  ushort4 o;
  o.x = f2bf(v.x); o.y = f2bf(v.y); o.z = f2bf(v.z); o.w = f2bf(v.w);
  *reinterpret_cast<ushort4*>(zbF + (size_t)g * 4096 + khi * 256 + lo * 8 + j0) = o;

  float dot = 0.f;
  if (row < BHALF) {
    float4 w = *reinterpret_cast<const float4*>(zj + (size_t)row * DDIM + k0);
    dot = fmaf(v.x, w.x, fmaf(v.y, w.y, fmaf(v.z, w.z, v.w * w.w)));
  }
#pragma unroll
  for (int m = 32; m >= 1; m >>= 1) dot += __shfl_xor(dot, m, 64);
  __shared__ float red[4];
  if ((threadIdx.x & 63) == 0) red[threadIdx.x >> 6] = dot;
  __syncthreads();
  if (threadIdx.x == 0) Pp[blockIdx.x] = red[0] + red[1] + red[2] + red[3];

  if (t < NROWS) S[t] = 0.f;
}

// ---------------------------------------------------------------------------
// k_main: wave holds 128 persistent rows as MFMA *B* operand (lane-indexed in
// C/D -> scalar row sums). Streams 32-col tiles as the A operand, coalesced
// frag loads from frag-major zbF. Single-buffer pipelined reload under the
// exp section. No LDS, no barriers.
//
// This revision (structure = round-0 known-good; 3 additive levers):
//  * exp section uses float2 packed math -> v_pk_fma_f32 / v_pk_add_f32
//    (fp32 "157 TF" on MI355X is the packed rate; halves fma/add instrs).
//  * odd (block^wave) parity sleeps ~256cy pre-loop: seeds anti-phase between
//    the 2 waves/SIMD so MFMA and exp sections of different waves overlap
//    (round-robin issue otherwise co-schedules identical waves).
//  * s_setprio(1) around MFMA chain-pairs (T5; phase-diverse independent
//    waves = the regime where it measured positive).
// NOTE: rounds 1-2 proved source-level interleaving of exp into the MFMA
// chains spills catastrophically (WRITE_SIZE 1MB->162MB). Don't.
// ---------------------------------------------------------------------------
template <bool MASK>
__device__ __forceinline__ void expAcc(const f32x16& acc, f32x2& s, int d, int hi) {
#pragma unroll
  for (int k = 0; k < 8; ++k) {
    f32x2 u;
    u.x = acc[2 * k];
    u.y = acc[2 * k + 1];
    const f32x2 c2v = {C2, C2};
    const f32x2 msv = {-MSHIFT, -MSHIFT};
    u = __builtin_elementwise_fma(u, c2v, msv);       // v_pk_fma_f32
    f32x2 e;
    e.x = fexp2(u.x);
    e.y = fexp2(u.y);
    if (MASK) {
      const int r0 = 2 * k, r1 = 2 * k + 1;
      if (((r0 & 3) + 8 * (r0 >> 2) + 4 * hi) == d) e.x = 0.f;  // C/D reg map
      if (((r1 & 3) + 8 * (r1 >> 2) + 4 * hi) == d) e.y = 0.f;
    }
    s += e;                                            // v_pk_add_f32
  }
}

__global__ __launch_bounds__(256, 2)
void k_main(const unsigned short* __restrict__ zbF, float* __restrict__ S) {
  const int wave = threadIdx.x >> 6;
  const int lane = threadIdx.x & 63;
  const int lo = lane & 31;
  const int hi = lane >> 5;
  const int rb = blockIdx.x & 31;       // 32 row blocks of 512 rows
  const int cc = blockIdx.x >> 5;       // 16 col chunks of 1024 cols
  const int row0w = rb * 512 + wave * 128;

  // persistent row frags (B operand): 4 row-tiles x 8 k-steps = 128 VGPRs
  bf16x8 b[4][8];
#pragma unroll
  for (int rt = 0; rt < 4; ++rt) {
    const unsigned short* bp = zbF + (size_t)((row0w >> 5) + rt) * 4096 + hi * 256 + lo * 8;
#pragma unroll
    for (int ks = 0; ks < 8; ++ks)
      b[rt][ks] = *reinterpret_cast<const bf16x8*>(bp + ks * 512);
  }

  const f32x16 kZ = {};                 // persistent zero C-operand
  f32x2 s[4];
#pragma unroll
  for (int rt = 0; rt < 4; ++rt) { s[rt].x = 0.f; s[rt].y = 0.f; }

  const int c0base = cc * 1024;
  const unsigned short* abase = zbF + (size_t)(c0base >> 5) * 4096 + hi * 256 + lo * 8;

  bf16x8 a[8];
#pragma unroll
  for (int ks = 0; ks < 8; ++ks)
    a[ks] = *reinterpret_cast<const bf16x8*>(abase + ks * 512);

  // seed anti-phase: half the waves on each SIMD delay ~256 cycles so their
  // MFMA sections land under the partner wave's exp sections.
  if (((blockIdx.x ^ wave) & 1) != 0) __builtin_amdgcn_s_sleep(4);

  for (int it = 0; it < 32; ++it) {
    const int c0 = c0base + it * 32;
    const int dr = c0 - row0w;
    const bool dg = (unsigned)dr < 128u;       // tile touches diagonal?
    const int rtd = dg ? (dr >> 5) : -1;

    // half 1: row-tiles 0,1
    __builtin_amdgcn_s_setprio(1);
    f32x16 acc0 = __builtin_amdgcn_mfma_f32_32x32x16_bf16(a[0], b[0][0], kZ, 0, 0, 0);
    f32x16 acc1 = __builtin_amdgcn_mfma_f32_32x32x16_bf16(a[0], b[1][0], kZ, 0, 0, 0);
#pragma unroll
    for (int ks = 1; ks < 8; ++ks) {
      acc0 = __builtin_amdgcn_mfma_f32_32x32x16_bf16(a[ks], b[0][ks], acc0, 0, 0, 0);
      acc1 = __builtin_amdgcn_mfma_f32_32x32x16_bf16(a[ks], b[1][ks], acc1, 0, 0, 0);
    }
    __builtin_amdgcn_s_setprio(0);
    if (!dg) {
      expAcc<false>(acc0, s[0], -1, hi);
      expAcc<false>(acc1, s[1], -1, hi);
    } else {
      expAcc<true>(acc0, s[0], rtd == 0 ? lo : -1, hi);
      expAcc<true>(acc1, s[1], rtd == 1 ? lo : -1, hi);
    }

    // half 2: row-tiles 2,3
    __builtin_amdgcn_s_setprio(1);
    acc0 = __builtin_amdgcn_mfma_f32_32x32x16_bf16(a[0], b[2][0], kZ, 0, 0, 0);
    acc1 = __builtin_amdgcn_mfma_f32_32x32x16_bf16(a[0], b[3][0], kZ, 0, 0, 0);
#pragma unroll
    for (int ks = 1; ks < 8; ++ks) {
      acc0 = __builtin_amdgcn_mfma_f32_32x32x16_bf16(a[ks], b[2][ks], acc0, 0, 0, 0);
      acc1 = __builtin_amdgcn_mfma_f32_32x32x16_bf16(a[ks], b[3][ks], acc1, 0, 0, 0);
    }
    __builtin_amdgcn_s_setprio(0);

    // pipelined single-buffer reload: a[] free after the chains above; the
    // vmcnt wait lands after the exp section below.
    if (it + 1 < 32) {
      const unsigned short* ap = abase + (size_t)(it + 1) * 4096;
#pragma unroll
      for (int ks = 0; ks < 8; ++ks)
        a[ks] = *reinterpret_cast<const bf16x8*>(ap + ks * 512);
    }

    if (!dg) {
      expAcc<false>(acc0, s[2], -1, hi);
      expAcc<false>(acc1, s[3], -1, hi);
    } else {
      expAcc<true>(acc0, s[2], rtd == 2 ? lo : -1, hi);
      expAcc<true>(acc1, s[3], rtd == 3 ? lo : -1, hi);
    }
  }

  // row sums: lane-local scalar + fold hi halves, one atomic per row per chunk
#pragma unroll
  for (int rt = 0; rt < 4; ++rt) {
    float v = s[rt].x + s[rt].y;
    v += __shfl_xor(v, 32, 64);
    if (hi == 0) atomicAdd(&S[row0w + rt * 32 + lo], v);
  }
}

// ---------------------------------------------------------------------------
// k_fin: out = ( LN2 * sum_k (M + log2 S_k)  -  4 * sum Pp ) / N
// Linear -> single fused block reduction (1024 threads).
// ---------------------------------------------------------------------------
__global__ void k_fin(const float* __restrict__ S, const float* __restrict__ Pp,
                      float* __restrict__ out) {
  const int t = threadIdx.x;            // 1024 threads
  float q = 0.f;
  for (int r = t; r < NROWS; r += 1024)
    q += LN2 * (MSHIFT + __log2f(S[r]));
  for (int r = t; r < PREPB; r += 1024)
    q -= 4.0f * Pp[r];
  __shared__ float red[1024];
  red[t] = q;
  __syncthreads();
  for (int s2 = 512; s2 > 0; s2 >>= 1) {
    if (t < s2) red[t] += red[t + s2];
    __syncthreads();
  }
  if (t == 0) out[0] = red[0] / (float)NROWS;
}

// ---------------------------------------------------------------------------
extern "C" void kernel_launch(void* const* d_in, const int* in_sizes, int n_in,
                              void* d_out, int out_size, void* d_ws, size_t ws_size,
                              hipStream_t stream) {
  const float* zi = (const float*)d_in[0];
  const float* zj = (const float*)d_in[1];
  unsigned short* zbF = (unsigned short*)d_ws;                     // 4 MB
  float* S  = (float*)((char*)d_ws + (size_t)NROWS * DDIM * 2);    // 64 KB
  float* Pp = S + NROWS;                                           // 8 KB
  float* out = (float*)d_out;

  hipLaunchKernelGGL(k_prep, dim3(PREPB), dim3(256), 0, stream, zi, zj, zbF, S, Pp);
  hipLaunchKernelGGL(k_main, dim3(512),  dim3(256), 0, stream, zbF, S);
  hipLaunchKernelGGL(k_fin,  dim3(1),    dim3(1024), 0, stream, S, Pp, out);
}